// Round 7
// baseline (155.146 us; speedup 1.0000x reference)
//
#include <hip/hip_runtime.h>
#include <hip/hip_bf16.h>
#include <hip/hip_cooperative_groups.h>
#include <cstdint>
#include <cstddef>

namespace cg = cooperative_groups;

// Problem constants: B=4, T=1024, E=512, H=64, d_k=8
#define T_DIM 1024
#define E_DIM 512

typedef short bf16x8 __attribute__((ext_vector_type(8)));
typedef float f32x4  __attribute__((ext_vector_type(4)));

// ---------------------------------------------------------------------------
// Fused kernel, cooperative launch: grid 256 x 1024 threads.
// Phase 1 (per-head MFMA attention, R6-verified): block = one head. proj
// staged in LDS (projA scaled by sqrt(scale*log2e) -> e = exp2(raw score);
// projT transposed/unscaled for the PV V-frag). Scores via 16x16x32 bf16
// MFMA (quad0 carries d=0..7); e-values feed the PV A-operand directly in
// the score-MFMA's k-permutation (pi trick, zero cross-lane traffic); B col
// 8 = ones yields den in output col 8. Writes attn_bf + w_bf to workspace.
// grid.sync()   (remainder was ~64us across 3 rounds regardless of combine
// shape -> inter-kernel drain/gap; fusion removes it)
// Phase 2 (combine GEMM): out[4096][512] = attn_bf @ w_bf^T + bias. Block =
// 64x128 out-tile (64*4 = 256 tiles), BK=32, 16 waves as 4x4 (wave=16x32,
// 2 MFMAs/iter). LDS reused from phase 1 (12KB < 33KB). Frag reads are
// wave-contiguous 1KB -> conflict-free.
// ---------------------------------------------------------------------------
__global__ __launch_bounds__(1024)
void qattn_fused(const float* __restrict__ x,
                 const float* __restrict__ theta,
                 const float* __restrict__ W,
                 const float* __restrict__ bias,
                 __hip_bfloat16* __restrict__ attn_bf, // ws [4096][512]
                 __hip_bfloat16* __restrict__ w_bf,    // ws [512][512]
                 float* __restrict__ out)              // [4096][512]
{
    // Phase1: projA 1024x8 (16384 B) + projT 8x1032 (16512 B) = 32896 B
    // Phase2: As 64x32 (4096 B) + Bs 128x32 (8192 B)          = 12288 B
    __shared__ __align__(16) char shraw[32896];

    const int bid  = blockIdx.x;        // 0..255
    const int tid  = threadIdx.x;       // 0..1023
    const int lane = tid & 63;
    const int wv   = tid >> 6;          // 0..15
    const int rlo  = lane & 15;
    const int quad = lane >> 4;

    // ================= Phase 1: attention for head `bid` =================
    {
        auto projA = (__hip_bfloat16 (*)[8])(shraw);            // [key][d]
        auto projT = (__hip_bfloat16 (*)[1032])(shraw + 16384); // [d][key]

        const int b = bid >> 6;
        const int h = bid & 63;

        // Folded W fp32->bf16 convert: threads 0..65535 cover 512*512/4.
        {
            const int gid = bid * 1024 + tid;
            if (gid < 65536) {
                const float4 v = *(const float4*)(W + gid * 4);
                alignas(8) __hip_bfloat16 ob[4] = {
                    __float2bfloat16(v.x), __float2bfloat16(v.y),
                    __float2bfloat16(v.z), __float2bfloat16(v.w)};
                *(uint2*)(w_bf + gid * 4) = *(const uint2*)ob;
            }
        }

        // sqrt((1/sqrt(8))*log2(e)): folds softmax scale + ln->log2 so
        // e = exp2(raw mfma score).
        const float SA = 0.7142255f;
        float ctT[8], ctA[8];
#pragma unroll
        for (int d = 0; d < 8; ++d) {
            ctT[d] = __cosf(theta[d]);
            ctA[d] = ctT[d] * SA;
        }

        // Stage full-head proj: 1024 rows, one per thread.
        const float* xb = x + (size_t)b * T_DIM * E_DIM + h * 8;
        {
            const int r = tid;
            const float4 v0 = *(const float4*)(xb + (size_t)r * E_DIM);
            const float4 v1 = *(const float4*)(xb + (size_t)r * E_DIM + 4);
            float pr[8] = {v0.x, v0.y, v0.z, v0.w, v1.x, v1.y, v1.z, v1.w};
            alignas(16) __hip_bfloat16 ra[8];
#pragma unroll
            for (int d = 0; d < 8; ++d) {
                const float c = __cosf(pr[d]);
                ra[d] = __float2bfloat16(c * ctA[d]);
                projT[d][r] = __float2bfloat16(c * ctT[d]);
            }
            *(uint4*)&projA[r][0] = *(const uint4*)ra;
        }
        __syncthreads();

        const bf16x8 z8 = {};
        bf16x8 ones8;
#pragma unroll
        for (int j = 0; j < 8; ++j) ones8[j] = (short)0x3f80;  // bf16 1.0

        const int q0 = wv * 64;
        bf16x8 bq[4];
#pragma unroll
        for (int tl = 0; tl < 4; ++tl)
            bq[tl] = (quad == 0)
                ? *(const bf16x8*)&projA[q0 + tl * 16 + rlo][0] : z8;

        f32x4 nacc[4] = {};

        for (int kc = 0; kc < 32; ++kc) {           // 32-key chunks
            const int key0 = kc * 32;
            // V-frag in pi order: cols {key0+quad*4+j} U {key0+16+quad*4+j}
            bf16x8 bv;
            if (rlo < 8) {
                const __hip_bfloat16* pt = &projT[rlo][key0 + quad * 4];
                union { uint2 u[2]; bf16x8 v; } uu;
                uu.u[0] = *(const uint2*)pt;
                uu.u[1] = *(const uint2*)(pt + 16);
                bv = uu.v;
            } else {
                bv = (rlo == 8) ? ones8 : z8;
            }
            const bf16x8 ka0 =
                (quad == 0) ? *(const bf16x8*)&projA[key0 + rlo][0] : z8;
            const bf16x8 ka1 =
                (quad == 0) ? *(const bf16x8*)&projA[key0 + 16 + rlo][0] : z8;

#pragma unroll
            for (int tl = 0; tl < 4; ++tl) {
                f32x4 s0 = __builtin_amdgcn_mfma_f32_16x16x32_bf16(
                    ka0, bq[tl], (f32x4){0.f, 0.f, 0.f, 0.f}, 0, 0, 0);
                f32x4 s1 = __builtin_amdgcn_mfma_f32_16x16x32_bf16(
                    ka1, bq[tl], (f32x4){0.f, 0.f, 0.f, 0.f}, 0, 0, 0);
                alignas(16) __hip_bfloat16 af8[8];
#pragma unroll
                for (int r = 0; r < 4; ++r) {
                    af8[r]     = __float2bfloat16(__builtin_amdgcn_exp2f(s0[r]));
                    af8[4 + r] = __float2bfloat16(__builtin_amdgcn_exp2f(s1[r]));
                }
                nacc[tl] = __builtin_amdgcn_mfma_f32_16x16x32_bf16(
                    *(const bf16x8*)af8, bv, nacc[tl], 0, 0, 0);
            }
        }

        // Epilogue: nacc[tl][r] = num[q=q0+tl*16+quad*4+r][d=rlo]; col8=den
        const int denSrc = (lane & 48) | 8;
#pragma unroll
        for (int tl = 0; tl < 4; ++tl) {
#pragma unroll
            for (int r = 0; r < 4; ++r) {
                const float den = __shfl(nacc[tl][r], denSrc);
                if (rlo < 8) {
                    const int trow = q0 + tl * 16 + quad * 4 + r;
                    attn_bf[(size_t)(b * T_DIM + trow) * E_DIM + h * 8 + rlo]
                        = __float2bfloat16(nacc[tl][r] / den);
                }
            }
        }
    }

    // ======================= grid-wide barrier ==========================
    cg::this_grid().sync();

    // ================= Phase 2: combine GEMM ============================
    {
        auto As = (__hip_bfloat16 (*)[32])(shraw);          // 64 rows
        auto Bs = (__hip_bfloat16 (*)[32])(shraw + 4096);   // 128 rows

        const int bm = bid >> 2;            // 0..63  (64-row tile)
        const int bn = bid & 3;             // 0..3   (128-col tile)
        const int m0 = (wv >> 2) * 16;      // wave row offset in tile
        const int n0 = (wv & 3) * 32;       // wave col offset in tile
        const int khi = quad * 8;           // k elements offset

        f32x4 acc[2] = {};

        for (int k0 = 0; k0 < E_DIM; k0 += 32) {
            if (k0) __syncthreads();
            if (tid < 256) {                // waves 0-3: stage A (64x32)
                const int row = tid >> 2;
                const int kc  = tid & 3;
                const __hip_bfloat16* gA =
                    attn_bf + (size_t)(bm * 64 + row) * E_DIM + k0 + kc * 8;
                char* lA = shraw + wv * 1024;   // wave-uniform base
                __builtin_amdgcn_global_load_lds(
                    (const __attribute__((address_space(1))) void*)gA,
                    (__attribute__((address_space(3))) void*)lA, 16, 0, 0);
            } else if (tid < 768) {         // waves 4-11: stage B (128x32)
                const int c   = tid - 256;
                const int row = c >> 2;
                const int kc  = c & 3;
                const __hip_bfloat16* gW =
                    w_bf + (size_t)(bn * 128 + row) * E_DIM + k0 + kc * 8;
                char* lB = shraw + 4096 + (wv - 4) * 1024;
                __builtin_amdgcn_global_load_lds(
                    (const __attribute__((address_space(1))) void*)gW,
                    (__attribute__((address_space(3))) void*)lB, 16, 0, 0);
            }
            __syncthreads();

            const bf16x8 af = *(const bf16x8*)&As[m0 + rlo][khi];
            bf16x8 bf[2];
#pragma unroll
            for (int j = 0; j < 2; ++j)
                bf[j] = *(const bf16x8*)&Bs[n0 + j * 16 + rlo][khi];
#pragma unroll
            for (int j = 0; j < 2; ++j)
                acc[j] = __builtin_amdgcn_mfma_f32_16x16x32_bf16(
                    af, bf[j], acc[j], 0, 0, 0);
        }

        // Epilogue: C/D layout col = rlo, row = quad*4 + r.
        const int row0 = bm * 64 + m0;
        const int col0 = bn * 128 + n0;
#pragma unroll
        for (int j = 0; j < 2; ++j) {
            const int col = col0 + j * 16 + rlo;
            const float bv = bias[col];
#pragma unroll
            for (int r = 0; r < 4; ++r)
                out[(size_t)(row0 + quad * 4 + r) * E_DIM + col]
                    = acc[j][r] + bv;
        }
    }
}

// ---------------------------------------------------------------------------
extern "C" void kernel_launch(void* const* d_in, const int* in_sizes, int n_in,
                              void* d_out, int out_size, void* d_ws,
                              size_t ws_size, hipStream_t stream)
{
    const float* x     = (const float*)d_in[0];  // [4,1024,512]
    const float* theta = (const float*)d_in[1];  // [8]
    const float* W     = (const float*)d_in[2];  // [512,512]
    const float* bias  = (const float*)d_in[3];  // [512]
    float* out = (float*)d_out;                  // [4,1024,512] fp32

    __hip_bfloat16* attn_bf = (__hip_bfloat16*)d_ws;
    __hip_bfloat16* w_bf    = (__hip_bfloat16*)((char*)d_ws + 4u * 1024u * 1024u);

    void* args[] = {(void*)&x, (void*)&theta, (void*)&W, (void*)&bias,
                    (void*)&attn_bf, (void*)&w_bf, (void*)&out};
    hipLaunchCooperativeKernel((const void*)qattn_fused, dim3(256), dim3(1024),
                               args, 0, stream);
}

// Round 8
// 117.093 us; speedup vs baseline: 1.3250x; 1.3250x over previous
//
#include <hip/hip_runtime.h>
#include <hip/hip_bf16.h>
#include <cstdint>
#include <cstddef>

// Problem constants: B=4, T=1024, E=512, H=64, d_k=8
#define T_DIM 1024
#define E_DIM 512

typedef short bf16x8 __attribute__((ext_vector_type(8)));
typedef float f32x4  __attribute__((ext_vector_type(4)));

// ---------------------------------------------------------------------------
// Kernel A: MFMA attention. R7->R8: REVERTED cooperative fusion (fixed
// ~56-64us non-kernel overhead is harness-side; fusion made both kernel and
// overhead worse). New: grid 512 = 256 heads x 2 query-halves, 1024 thr ->
// 2 blocks/CU = 32 waves/CU (was 16) to hide the score->exp2->cvt->PV
// serial-chain latency (R6 stalled ~22us at VALUBusy 51%).
// Math identical to R5/R6 (verified): scores via 16x16x32 bf16 MFMA (quad0
// carries d=0..7; projA pre-scaled by sqrt(scale*log2e) so e = exp2(raw
// score)); e-values feed the PV A-operand directly in the score-MFMA's
// k-permutation (pi trick, zero cross-lane traffic, zero bank conflicts);
// V B-frag reads projT in the same pi order; B col 8 = ones -> den free in
// output col 8. Each block stages the full head's proj (redundant across the
// 2 half-blocks; ~2us total extra VALU, buys 2x latency hiding).
// ---------------------------------------------------------------------------
__global__ __launch_bounds__(1024)
void qattn_mfma(const float* __restrict__ x,
                const float* __restrict__ theta,
                const float* __restrict__ W,
                __hip_bfloat16* __restrict__ attn_out, // [4096][512] bf16
                __hip_bfloat16* __restrict__ w_bf)     // [512][512] bf16
{
    __shared__ __hip_bfloat16 projA[T_DIM][8];     // [key][d] scaled, 16 KB
    __shared__ __hip_bfloat16 projT[8][1032];      // [d][key] unscaled, 16.1 KB

    const int bid   = blockIdx.x;       // 0..511
    const int head  = bid >> 1;         // 0..255
    const int qhalf = bid & 1;
    const int b     = head >> 6;
    const int h     = head & 63;
    const int tid   = threadIdx.x;      // 0..1023
    const int lane  = tid & 63;
    const int wv    = tid >> 6;         // 0..15
    const int rlo   = lane & 15;
    const int quad  = lane >> 4;

    // Folded W fp32->bf16 convert: blocks 0..63 cover 512*512/4 threads.
    {
        const int gid = bid * 1024 + tid;
        if (gid < 65536) {
            const float4 v = *(const float4*)(W + gid * 4);
            alignas(8) __hip_bfloat16 ob[4] = {
                __float2bfloat16(v.x), __float2bfloat16(v.y),
                __float2bfloat16(v.z), __float2bfloat16(v.w)};
            *(uint2*)(w_bf + gid * 4) = *(const uint2*)ob;
        }
    }

    // sqrt((1/sqrt(8))*log2(e)): folds softmax scale + ln->log2 into the
    // score operands so e = exp2(raw mfma output).
    const float SA = 0.7142255f;
    float ctT[8], ctA[8];
#pragma unroll
    for (int d = 0; d < 8; ++d) {
        ctT[d] = __cosf(theta[d]);
        ctA[d] = ctT[d] * SA;
    }

    // Stage full-head proj: 1024 rows, one per thread.
    const float* xb = x + (size_t)b * T_DIM * E_DIM + h * 8;
    {
        const int r = tid;
        const float4 v0 = *(const float4*)(xb + (size_t)r * E_DIM);
        const float4 v1 = *(const float4*)(xb + (size_t)r * E_DIM + 4);
        float pr[8] = {v0.x, v0.y, v0.z, v0.w, v1.x, v1.y, v1.z, v1.w};
        alignas(16) __hip_bfloat16 ra[8];
#pragma unroll
        for (int d = 0; d < 8; ++d) {
            const float c = __cosf(pr[d]);
            ra[d] = __float2bfloat16(c * ctA[d]);
            projT[d][r] = __float2bfloat16(c * ctT[d]);
        }
        *(uint4*)&projA[r][0] = *(const uint4*)ra;
    }
    __syncthreads();

    const bf16x8 z8 = {};
    bf16x8 ones8;
#pragma unroll
    for (int j = 0; j < 8; ++j) ones8[j] = (short)0x3f80;  // bf16 1.0

    // This wave owns 32 queries: q0..q0+31 (2 tiles of 16).
    const int q0 = qhalf * 512 + wv * 32;
    bf16x8 bq[2];
#pragma unroll
    for (int tl = 0; tl < 2; ++tl)
        bq[tl] = (quad == 0) ? *(const bf16x8*)&projA[q0 + tl * 16 + rlo][0]
                             : z8;

    f32x4 nacc[2] = {};

    for (int kc = 0; kc < 32; ++kc) {           // 32-key chunks
        const int key0 = kc * 32;
        // V-frag in pi order: cols {key0+quad*4+j} U {key0+16+quad*4+j}.
        bf16x8 bv;
        if (rlo < 8) {
            const __hip_bfloat16* pt = &projT[rlo][key0 + quad * 4];
            union { uint2 u[2]; bf16x8 v; } uu;
            uu.u[0] = *(const uint2*)pt;
            uu.u[1] = *(const uint2*)(pt + 16);
            bv = uu.v;
        } else {
            bv = (rlo == 8) ? ones8 : z8;
        }
        // Key A-frags for the two 16-key halves.
        const bf16x8 ka0 =
            (quad == 0) ? *(const bf16x8*)&projA[key0 + rlo][0] : z8;
        const bf16x8 ka1 =
            (quad == 0) ? *(const bf16x8*)&projA[key0 + 16 + rlo][0] : z8;

#pragma unroll
        for (int tl = 0; tl < 2; ++tl) {
            f32x4 s0 = __builtin_amdgcn_mfma_f32_16x16x32_bf16(
                ka0, bq[tl], (f32x4){0.f, 0.f, 0.f, 0.f}, 0, 0, 0);
            f32x4 s1 = __builtin_amdgcn_mfma_f32_16x16x32_bf16(
                ka1, bq[tl], (f32x4){0.f, 0.f, 0.f, 0.f}, 0, 0, 0);
            alignas(16) __hip_bfloat16 af8[8];
#pragma unroll
            for (int r = 0; r < 4; ++r) {
                af8[r]     = __float2bfloat16(__builtin_amdgcn_exp2f(s0[r]));
                af8[4 + r] = __float2bfloat16(__builtin_amdgcn_exp2f(s1[r]));
            }
            nacc[tl] = __builtin_amdgcn_mfma_f32_16x16x32_bf16(
                *(const bf16x8*)af8, bv, nacc[tl], 0, 0, 0);
        }
    }

    // Epilogue: nacc[tl][r] = num[q=q0+tl*16+quad*4+r][d=rlo]; col 8 = den.
    const int denSrc = (lane & 48) | 8;   // lane with rlo==8 in same quad
#pragma unroll
    for (int tl = 0; tl < 2; ++tl) {
#pragma unroll
        for (int r = 0; r < 4; ++r) {
            const float den = __shfl(nacc[tl][r], denSrc);
            if (rlo < 8) {
                const int trow = q0 + tl * 16 + quad * 4 + r;
                attn_out[(size_t)(b * T_DIM + trow) * E_DIM + h * 8 + rlo] =
                    __float2bfloat16(nacc[tl][r] / den);
            }
        }
    }
}

// ---------------------------------------------------------------------------
// Kernel B: out[4096][512] = attn_bf16 @ W_bf16^T + bias (fp32 out).
// R6's verified version, unchanged: 128x64 tile, BK=64, grid 32x8, XOR-
// swizzled k-chunks (slot kc^(row&7)) for conflict-free b128 frag reads.
// ---------------------------------------------------------------------------
#define BM 128
#define BN 64
#define BK 64

__global__ __launch_bounds__(256, 2)
void combine_gemm(const __hip_bfloat16* __restrict__ A,  // [4096][512]
                  const __hip_bfloat16* __restrict__ Wb, // [512][512] (N,K)
                  const float* __restrict__ bias,        // [512]
                  float* __restrict__ out)               // [4096][512]
{
    __shared__ __hip_bfloat16 As[BM][BK];  // 16 KB
    __shared__ __hip_bfloat16 Bs[BN][BK];  // 8 KB

    const int tid  = threadIdx.x;
    const int lane = tid & 63;
    const int wave = tid >> 6;
    const int bm   = blockIdx.x;          // 0..31
    const int bn   = blockIdx.y;          // 0..7
    const int wm   = (wave & 1) * 64;
    const int wn   = (wave >> 1) * 32;
    const int rlo  = lane & 15;
    const int quad = lane >> 4;

    f32x4 acc[4][2] = {};

    for (int k0 = 0; k0 < E_DIM; k0 += BK) {
        if (k0) __syncthreads();
        // A: 128 rows x 8 chunks(16B) = 1024 chunks, 4 passes of 256.
#pragma unroll
        for (int p = 0; p < 4; ++p) {
            const int c   = p * 256 + tid;
            const int row = c >> 3;
            const int kcs = c & 7;                 // LDS slot
            const int kc  = kcs ^ (row & 7);       // global chunk (swizzle)
            const __hip_bfloat16* gA =
                A + (size_t)(bm * BM + row) * E_DIM + k0 + kc * 8;
            char* lA = (char*)As + (size_t)(p * 256 + wave * 64) * 16;
            __builtin_amdgcn_global_load_lds(
                (const __attribute__((address_space(1))) void*)gA,
                (__attribute__((address_space(3))) void*)lA, 16, 0, 0);
        }
        // B: 64 rows x 8 chunks = 512 chunks, 2 passes of 256.
#pragma unroll
        for (int p = 0; p < 2; ++p) {
            const int c   = p * 256 + tid;
            const int row = c >> 3;
            const int kcs = c & 7;
            const int kc  = kcs ^ (row & 7);
            const __hip_bfloat16* gW =
                Wb + (size_t)(bn * BN + row) * E_DIM + k0 + kc * 8;
            char* lB = (char*)Bs + (size_t)(p * 256 + wave * 64) * 16;
            __builtin_amdgcn_global_load_lds(
                (const __attribute__((address_space(1))) void*)gW,
                (__attribute__((address_space(3))) void*)lB, 16, 0, 0);
        }
        __syncthreads();

#pragma unroll
        for (int ks = 0; ks < 2; ++ks) {
            const int kci  = ks * 4 + quad;              // wanted k-chunk
            const int koff = (kci ^ (rlo & 7)) * 8;      // swizzled LDS off
            bf16x8 af[4], bf[2];
#pragma unroll
            for (int i = 0; i < 4; ++i)
                af[i] = *(const bf16x8*)&As[wm + i * 16 + rlo][koff];
#pragma unroll
            for (int j = 0; j < 2; ++j)
                bf[j] = *(const bf16x8*)&Bs[wn + j * 16 + rlo][koff];
#pragma unroll
            for (int i = 0; i < 4; ++i)
#pragma unroll
                for (int j = 0; j < 2; ++j)
                    acc[i][j] = __builtin_amdgcn_mfma_f32_16x16x32_bf16(
                        af[i], bf[j], acc[i][j], 0, 0, 0);
        }
    }

    // Epilogue: C/D layout col = lane&15, row = quad*4 + reg.
    const int row0 = bm * BM + wm;
    const int col0 = bn * BN + wn;
#pragma unroll
    for (int j = 0; j < 2; ++j) {
        const int col = col0 + j * 16 + rlo;
        const float bv = bias[col];
#pragma unroll
        for (int i = 0; i < 4; ++i) {
            const int rbase = row0 + i * 16 + quad * 4;
#pragma unroll
            for (int r = 0; r < 4; ++r)
                out[(size_t)(rbase + r) * E_DIM + col] = acc[i][j][r] + bv;
        }
    }
}

// ---------------------------------------------------------------------------
extern "C" void kernel_launch(void* const* d_in, const int* in_sizes, int n_in,
                              void* d_out, int out_size, void* d_ws,
                              size_t ws_size, hipStream_t stream)
{
    const float* x     = (const float*)d_in[0];  // [4,1024,512]
    const float* theta = (const float*)d_in[1];  // [8]
    const float* W     = (const float*)d_in[2];  // [512,512]
    const float* bias  = (const float*)d_in[3];  // [512]
    float* out = (float*)d_out;                  // [4,1024,512] fp32

    __hip_bfloat16* attn_bf = (__hip_bfloat16*)d_ws;
    __hip_bfloat16* w_bf    = (__hip_bfloat16*)((char*)d_ws + 4u * 1024u * 1024u);

    hipLaunchKernelGGL(qattn_mfma, dim3(512), dim3(1024), 0, stream,
                       x, theta, W, attn_bf, w_bf);
    hipLaunchKernelGGL(combine_gemm, dim3(32, 8), dim3(256), 0, stream,
                       attn_bf, w_bf, bias, out);
}